// Round 1
// baseline (2741.309 us; speedup 1.0000x reference)
//
#include <hip/hip_runtime.h>
#include <cstdint>
#include <cstddef>

typedef __bf16 bf16_t;
typedef __attribute__((ext_vector_type(8))) __bf16 bf16x8;
typedef __attribute__((ext_vector_type(4))) __bf16 bf16x4;
typedef __attribute__((ext_vector_type(4))) float f32x4;

#define TSTEPS 20
#define HDIM 256
#define GDIM 1024   // 4H

static __device__ __forceinline__ f32x4 mfma_(bf16x8 a, bf16x8 b, f32x4 c) {
    return __builtin_amdgcn_mfma_f32_16x16x32_bf16(a, b, c, 0, 0, 0);
}
static __device__ __forceinline__ float sig_(float x) {
    return __builtin_amdgcn_rcpf(1.0f + __expf(-x));
}
static __device__ __forceinline__ float tanh_(float x) {
    return 2.0f * __builtin_amdgcn_rcpf(1.0f + __expf(-2.0f * x)) - 1.0f;
}

// ---------------------------------------------------------------------------
// Pack row-major fp32 weights [K][cols] into MFMA B-fragment tiles (bf16).
// Tile index = nt*ktiles + kt. Within tile: [lane][e], 8 bf16 (16B) per lane.
// Element (lane,e) = src[kt*32 + (lane>>4)*8 + e][nt*16 + (lane&15)]
// (16x16x32 bf16 B-layout: col = lane&15, k = (lane>>4)*8 + e, contiguous-8;
//  layout verified by learn_hip m92/m97 ref-checked GEMM.)
// ---------------------------------------------------------------------------
__global__ void pack_b_kernel(const float* __restrict__ srcA, int ldA,
                              const float* __restrict__ srcB, int ldB,
                              int split, int ntiles, int ktiles,
                              bf16_t* __restrict__ dst)
{
    int tid = blockIdx.x * blockDim.x + threadIdx.x;
    int total = ntiles * ktiles * 64;
    if (tid >= total) return;
    int lane = tid & 63;
    int tile = tid >> 6;
    int kt = tile % ktiles;
    int nt = tile / ktiles;
    int c  = (nt << 4) + (lane & 15);
    int k0 = (kt << 5) + ((lane >> 4) << 3);
    bf16x8 v;
    #pragma unroll
    for (int e = 0; e < 8; ++e) {
        int k = k0 + e;
        float x;
        if (c < split) x = srcA[(size_t)k * ldA + c];
        else           x = srcB[(size_t)k * ldB + (c - split)];
        v[e] = (bf16_t)x;
    }
    *reinterpret_cast<bf16x8*>(&dst[(size_t)tid * 8]) = v;
}

// ---------------------------------------------------------------------------
// Persistent 2-layer LSTM scan. BM=32 rows/block, grid=256, 4 waves/block.
// Wave w owns H-columns [w*64, w*64+64) -> gate tiles ntg = g*16 + w*4 + ht.
// h1/h2 in LDS (bf16, double-buffered, XOR-swizzled); c1/c2 in fp32 VGPRs.
// ---------------------------------------------------------------------------
__global__ __launch_bounds__(256, 1)
void lstm_scan_kernel(const float* __restrict__ z1, const float* __restrict__ z2,
                      const float* __restrict__ W1, const float* __restrict__ b1,
                      const float* __restrict__ b2,
                      const bf16_t* __restrict__ U1p, const bf16_t* __restrict__ B2p,
                      float* __restrict__ out)
{
    __shared__ alignas(16) bf16_t xw1T[GDIM * 32];      // [col][row], swizzled, 64KB
    __shared__ alignas(16) bf16_t h1buf[2 * 32 * HDIM]; // ping-pong, 32KB
    __shared__ alignas(16) bf16_t h2buf[2 * 32 * HDIM]; // ping-pong, 32KB
    __shared__ alignas(16) float  zT[64 * 32];          // z_cat transposed, 8KB

    const int tid  = threadIdx.x;
    const int lane = tid & 63;
    const int wv   = tid >> 6;      // wave 0..3
    const int l15  = lane & 15;
    const int lq   = lane >> 4;     // 0..3
    const int w4   = wv << 2;
    const int b0   = blockIdx.x << 5;

    // ---- stage 0: load z_cat (transposed) + zero h buffers ----
    for (int i = tid; i < 2048; i += 256) {
        int r = i >> 6, k = i & 63;
        float v = (k < 32) ? z1[(size_t)(b0 + r) * 32 + k]
                           : z2[(size_t)(b0 + r) * 32 + (k - 32)];
        zT[k * 32 + r] = v;
    }
    for (int i = tid; i < 8192; i += 256) {
        h1buf[i] = (bf16_t)0.0f;
        h2buf[i] = (bf16_t)0.0f;
    }
    __syncthreads();

    // ---- stage 1: xw1 = z_cat @ W1 + b1 (fp32), store transposed bf16 in LDS ----
    // thread owns cols {tid, tid+256, tid+512, tid+768}; z via LDS broadcast b128.
    for (int cc = 0; cc < 4; ++cc) {
        const int c = tid + (cc << 8);
        float acc[32];
        #pragma unroll
        for (int r = 0; r < 32; ++r) acc[r] = 0.0f;
        for (int k = 0; k < 64; ++k) {
            float wk = W1[k * GDIM + c];
            const f32x4* zp = reinterpret_cast<const f32x4*>(&zT[k * 32]);
            #pragma unroll
            for (int rq = 0; rq < 8; ++rq) {
                f32x4 z4 = zp[rq];
                #pragma unroll
                for (int j = 0; j < 4; ++j) acc[rq * 4 + j] += z4[j] * wk;
            }
        }
        const float bb = b1[c];
        const int sw = (c & 7) << 2;
        #pragma unroll
        for (int r = 0; r < 32; ++r)
            xw1T[((c << 5) + r) ^ sw] = (bf16_t)(acc[r] + bb);
    }

    // b2 per (gate, h-tile), constant over steps
    float b2r[4][4];
    #pragma unroll
    for (int g = 0; g < 4; ++g)
        #pragma unroll
        for (int ht = 0; ht < 4; ++ht)
            b2r[g][ht] = b2[(((g << 4) + w4 + ht) << 4) + l15];

    f32x4 c1[2][4], c2[2][4];
    #pragma unroll
    for (int mt = 0; mt < 2; ++mt)
        #pragma unroll
        for (int ht = 0; ht < 4; ++ht) {
            c1[mt][ht] = (f32x4){0.f, 0.f, 0.f, 0.f};
            c2[mt][ht] = (f32x4){0.f, 0.f, 0.f, 0.f};
        }

    __syncthreads();

    bf16x8 af[2][16];
    const size_t outbase = (size_t)b0 * (TSTEPS * HDIM);

    for (int t = 0; t < TSTEPS; ++t) {
        const int cur = (t & 1) << 13;   // ping-pong offset (elements)
        const int nxt = 8192 - cur;

        // ---- A-fragments of h1_old ----
        #pragma unroll
        for (int mt = 0; mt < 2; ++mt)
            #pragma unroll
            for (int kt = 0; kt < 8; ++kt) {
                int row = (mt << 4) + l15;
                int k0  = (kt << 5) + (lq << 3);
                int off = (((row << 8) + k0)) ^ ((row & 7) << 3);
                af[mt][kt] = *reinterpret_cast<const bf16x8*>(&h1buf[cur + off]);
            }

        // ---- layer 1: gates = xw1 + h1_old @ U1 ; update h1,c1 ----
        #pragma unroll
        for (int ht = 0; ht < 4; ++ht) {
            f32x4 ag[2][4];
            #pragma unroll
            for (int g = 0; g < 4; ++g) {
                const int ntg  = (g << 4) + w4 + ht;
                const int colb = (ntg << 4) + l15;
                {
                    const int sw = (colb & 7) << 2;
                    int idx0 = ((colb << 5) + (lq << 2)) ^ sw;
                    int idx1 = ((colb << 5) + 16 + (lq << 2)) ^ sw;
                    bf16x4 v0 = *reinterpret_cast<const bf16x4*>(&xw1T[idx0]);
                    bf16x4 v1 = *reinterpret_cast<const bf16x4*>(&xw1T[idx1]);
                    f32x4 a0, a1;
                    #pragma unroll
                    for (int j = 0; j < 4; ++j) { a0[j] = (float)v0[j]; a1[j] = (float)v1[j]; }
                    ag[0][g] = a0; ag[1][g] = a1;
                }
                const bf16x8* bp = reinterpret_cast<const bf16x8*>(U1p) + ((ntg << 3) << 6) + lane;
                #pragma unroll
                for (int kt = 0; kt < 8; ++kt) {
                    bf16x8 bfr = bp[kt << 6];
                    ag[0][g] = mfma_(af[0][kt], bfr, ag[0][g]);
                    ag[1][g] = mfma_(af[1][kt], bfr, ag[1][g]);
                }
            }
            const int col = ((w4 + ht) << 4) + l15;
            #pragma unroll
            for (int mt = 0; mt < 2; ++mt)
                #pragma unroll
                for (int j = 0; j < 4; ++j) {
                    float iv = sig_(ag[mt][0][j]);
                    float fv = sig_(ag[mt][1][j]);
                    float gv = tanh_(ag[mt][2][j]);
                    float ov = sig_(ag[mt][3][j]);
                    float cn = fv * c1[mt][ht][j] + iv * gv;
                    c1[mt][ht][j] = cn;
                    float hn = ov * tanh_(cn);
                    int row = (mt << 4) + (lq << 2) + j;
                    h1buf[nxt + (((row << 8) + col) ^ ((row & 7) << 3))] = (bf16_t)hn;
                }
        }
        __syncthreads();   // h1_new visible to all waves

        // ---- A-fragments: half0 = h1_new, half1 = h2_old ----
        #pragma unroll
        for (int mt = 0; mt < 2; ++mt)
            #pragma unroll
            for (int kt = 0; kt < 8; ++kt) {
                int row = (mt << 4) + l15;
                int k0  = (kt << 5) + (lq << 3);
                int off = (((row << 8) + k0)) ^ ((row & 7) << 3);
                af[mt][kt]     = *reinterpret_cast<const bf16x8*>(&h1buf[nxt + off]);
                af[mt][8 + kt] = *reinterpret_cast<const bf16x8*>(&h2buf[cur + off]);
            }

        // ---- layer 2: gates = b2 + h1_new @ W2 + h2_old @ U2 ; update h2,c2 ----
        #pragma unroll
        for (int ht = 0; ht < 4; ++ht) {
            f32x4 ag[2][4];
            #pragma unroll
            for (int g = 0; g < 4; ++g) {
                const int ntg = (g << 4) + w4 + ht;
                const float bb = b2r[g][ht];
                ag[0][g] = (f32x4){bb, bb, bb, bb};
                ag[1][g] = (f32x4){bb, bb, bb, bb};
                const bf16x8* bp0 = reinterpret_cast<const bf16x8*>(B2p) + ((ntg << 3) << 6) + lane;
                const bf16x8* bp1 = reinterpret_cast<const bf16x8*>(B2p) + (((64 + ntg) << 3) << 6) + lane;
                #pragma unroll
                for (int kt = 0; kt < 8; ++kt) {
                    bf16x8 bfr = bp0[kt << 6];
                    ag[0][g] = mfma_(af[0][kt], bfr, ag[0][g]);
                    ag[1][g] = mfma_(af[1][kt], bfr, ag[1][g]);
                }
                #pragma unroll
                for (int kt = 0; kt < 8; ++kt) {
                    bf16x8 bfr = bp1[kt << 6];
                    ag[0][g] = mfma_(af[0][8 + kt], bfr, ag[0][g]);
                    ag[1][g] = mfma_(af[1][8 + kt], bfr, ag[1][g]);
                }
            }
            const int col = ((w4 + ht) << 4) + l15;
            #pragma unroll
            for (int mt = 0; mt < 2; ++mt)
                #pragma unroll
                for (int j = 0; j < 4; ++j) {
                    float iv = sig_(ag[mt][0][j]);
                    float fv = sig_(ag[mt][1][j]);
                    float gv = tanh_(ag[mt][2][j]);
                    float ov = sig_(ag[mt][3][j]);
                    float cn = fv * c2[mt][ht][j] + iv * gv;
                    c2[mt][ht][j] = cn;
                    float hn = ov * tanh_(cn);
                    int row = (mt << 4) + (lq << 2) + j;
                    h2buf[nxt + (((row << 8) + col) ^ ((row & 7) << 3))] = (bf16_t)hn;
                    out[outbase + (size_t)row * (TSTEPS * HDIM) + t * HDIM + col] = hn;
                }
        }
        __syncthreads();   // h2_new visible before next step
    }
}

// ---------------------------------------------------------------------------
// Projection: x_mu = out@Wmu+bmu, x_lv = out@Wlv+blv,
//             x_sample = eps*exp(0.5*x_mu) + x_lv   (reference swaps args!)
// Block = 128 rows (4 waves x 32), Wpp = packed [Wmu|Wlv] (10 N-tiles of 16).
// ---------------------------------------------------------------------------
__global__ __launch_bounds__(256, 1)
void proj_kernel(const float* __restrict__ outp, const float* __restrict__ eps,
                 const float* __restrict__ bmu, const float* __restrict__ blv,
                 const bf16_t* __restrict__ Wpp,
                 float* __restrict__ xmu, float* __restrict__ xlv, float* __restrict__ xsm)
{
    const int tid = threadIdx.x, lane = tid & 63, wv = tid >> 6;
    const int l15 = lane & 15, lq = lane >> 4;
    const size_t r0 = (size_t)blockIdx.x * 128 + (size_t)wv * 32;

    bf16x8 af[2][8];
    #pragma unroll
    for (int mt = 0; mt < 2; ++mt)
        #pragma unroll
        for (int kt = 0; kt < 8; ++kt) {
            const float* p = &outp[(r0 + (mt << 4) + l15) * 256 + (kt << 5) + (lq << 3)];
            f32x4 x0 = *reinterpret_cast<const f32x4*>(p);
            f32x4 x1 = *reinterpret_cast<const f32x4*>(p + 4);
            bf16x8 a;
            #pragma unroll
            for (int j = 0; j < 4; ++j) { a[j] = (bf16_t)x0[j]; a[4 + j] = (bf16_t)x1[j]; }
            af[mt][kt] = a;
        }

    f32x4 acc[2][10];
    #pragma unroll
    for (int mt = 0; mt < 2; ++mt)
        #pragma unroll
        for (int nt = 0; nt < 10; ++nt) acc[mt][nt] = (f32x4){0.f, 0.f, 0.f, 0.f};

    #pragma unroll
    for (int nt = 0; nt < 10; ++nt) {
        const bf16x8* bp = reinterpret_cast<const bf16x8*>(Wpp) + ((nt << 3) << 6) + lane;
        #pragma unroll
        for (int kt = 0; kt < 8; ++kt) {
            bf16x8 b = bp[kt << 6];
            acc[0][nt] = mfma_(af[0][kt], b, acc[0][nt]);
            acc[1][nt] = mfma_(af[1][kt], b, acc[1][nt]);
        }
    }

    #pragma unroll
    for (int mt = 0; mt < 2; ++mt)
        #pragma unroll
        for (int nt = 0; nt < 5; ++nt) {
            const int col = (nt << 4) + l15;   // 0..79
            const float bm = bmu[col], bl = blv[col];
            #pragma unroll
            for (int j = 0; j < 4; ++j) {
                size_t row = r0 + (mt << 4) + (lq << 2) + j;
                float mu = acc[mt][nt][j] + bm;
                float lv = acc[mt][5 + nt][j] + bl;
                size_t o = row * 80 + col;
                float sm = eps[o] * __expf(0.5f * mu) + lv;
                xmu[o] = mu; xlv[o] = lv; xsm[o] = sm;
            }
        }
}

// ---------------------------------------------------------------------------
extern "C" void kernel_launch(void* const* d_in, const int* in_sizes, int n_in,
                              void* d_out, int out_size, void* d_ws, size_t ws_size,
                              hipStream_t stream) {
    const float* z1  = (const float*)d_in[1];
    const float* z2  = (const float*)d_in[2];
    const float* eps = (const float*)d_in[3];
    const float* W1  = (const float*)d_in[4];
    const float* U1  = (const float*)d_in[5];
    const float* b1  = (const float*)d_in[6];
    const float* W2  = (const float*)d_in[7];
    const float* U2  = (const float*)d_in[8];
    const float* b2  = (const float*)d_in[9];
    const float* Wmu = (const float*)d_in[10];
    const float* bmu = (const float*)d_in[11];
    const float* Wlv = (const float*)d_in[12];
    const float* blv = (const float*)d_in[13];

    float* out0 = (float*)d_out;
    const size_t N_OUT = (size_t)8192 * 20 * 256;   // 41943040
    const size_t N_F   = (size_t)8192 * 20 * 80;    // 13107200
    float* xmu = out0 + N_OUT;
    float* xlv = xmu + N_F;
    float* xsm = xlv + N_F;

    bf16_t* U1p = (bf16_t*)d_ws;            // 64*8*64*8 = 262144 elems
    bf16_t* B2p = U1p + 262144;             // 2 halves x 262144
    bf16_t* Wpp = U1p + 786432;             // 10*8*64*8 = 40960 elems

    // Pack weights into MFMA B-fragment order (bf16).
    pack_b_kernel<<<128, 256, 0, stream>>>(U1, 1024, U1, 1024, 1 << 30, 64, 8, U1p);
    pack_b_kernel<<<128, 256, 0, stream>>>(W2, 1024, W2, 1024, 1 << 30, 64, 8, B2p);
    pack_b_kernel<<<128, 256, 0, stream>>>(U2, 1024, U2, 1024, 1 << 30, 64, 8, B2p + 262144);
    pack_b_kernel<<<20, 256, 0, stream>>>(Wmu, 80, Wlv, 80, 80, 10, 8, Wpp);

    lstm_scan_kernel<<<256, 256, 0, stream>>>(z1, z2, W1, b1, b2, U1p, B2p, out0);
    proj_kernel<<<1280, 256, 0, stream>>>(out0, eps, bmu, blv, Wpp, xmu, xlv, xsm);
}